// Round 11
// baseline (140.290 us; speedup 1.0000x reference)
//
#include <hip/hip_runtime.h>
#include <hip/hip_bf16.h>

// ---------------------------------------------------------------------------
// HiddenEdgeDistanceMLP on MI355X (gfx950)
//
// reference:  s = s_lig[l] + s_poc[p]          [E,256]
//             h1 = silu(s @ W1.T + b1)         [E,128]
//             h2 = silu(h1 @ W2.T + b2)        [E,64]
//             out = relu(h2 @ W3.T + b3)       [E]
//
// Factorization: Z = concat(s_lig, s_poc) @ W1.T precomputed once (proj, fp32,
// hi/lo-split MFMA so Z is near-exact); b1 folded into ligand rows. Edge
// structure is block-diagonal and regular:
//   e = (b*32 + i)*160 + j,  l[e] = b*32+i,  p[e] = b*160+j
//
// edge v11 = v10 with the prefetch-address bug fixed. v10 FAILED (absmax
// 0.29) because the prefetch both used i0 (which grows with pair) AND bumped
// lgbase each pair -> effective row widx*8 + 3*pair + 2 instead of
// widx*8 + 2*pair + 2; atoms 4..7 consumed wrong rows. Fix: absolute
// addressing lrn = lgbase + (i0+2)*H1DIM, no base bump.
// v10 mechanisms kept:
//  * K-loop processes 2 atoms per pass: one set of W2-frag + pocket LDS
//    reads feeds both atoms (per-ks overhead halved; 8 indep MFMAs/ks);
//    prefetch of the next pair reuses the dead lg buffers.
//  * b2 folded into acc init - kills epilogue adds.
//  * single rhu-bf16 h1 + 1 MFMA/nt (R9, absmax unchanged 1.95e-3).
// Kept: 1280-block grid, pocket rows + W2 B-frags in LDS (R6), DPP rowsum +
// perm packing (R8), prefetch-under-epilogue (R7), no min-waves bound (R3).
// ---------------------------------------------------------------------------

#define B_CPLX   128
#define NLB      32
#define NPB      160
#define SDIM     256
#define H1DIM    128
#define NL_TOT   (B_CPLX * NLB)         // 4096
#define NP_TOT   (B_CPLX * NPB)         // 20480
#define NROWS    (NL_TOT + NP_TOT)      // 24576
#define E_TOT    (B_CPLX * NLB * NPB)   // 655360

#define W1_LDS_STRIDE 264               // 256 + 8 bf16 pad
#define JT_CHUNK 16                     // pocket rows per block
#define ZP_STRIDE 132                   // 128 + 4 f32 pad

typedef __bf16 bf16x8 __attribute__((ext_vector_type(8)));
typedef unsigned short ushortx8 __attribute__((ext_vector_type(8)));
typedef unsigned short ushortx4 __attribute__((ext_vector_type(4)));
typedef unsigned uintx4 __attribute__((ext_vector_type(4)));
typedef float f32x4 __attribute__((ext_vector_type(4)));

__device__ __forceinline__ unsigned short f2bf(float f) {
    unsigned u = __builtin_bit_cast(unsigned, f);
    u += 0x7FFFu + ((u >> 16) & 1u);          // round-to-nearest-even
    return (unsigned short)(u >> 16);
}

// v_perm_b32: pack hi16(x0) low, hi16(x1) high (1 op)
__device__ __forceinline__ unsigned perm_hi16u(unsigned u0, unsigned u1) {
    return __builtin_amdgcn_perm(u1, u0, 0x07060302u);
}

// round-half-up bf16 pair pack: bitpattern + 0x8000 then take hi16.
__device__ __forceinline__ unsigned pack2_rhu(float x0, float x1) {
    unsigned u0 = __builtin_bit_cast(unsigned, x0) + 0x8000u;
    unsigned u1 = __builtin_bit_cast(unsigned, x1) + 0x8000u;
    return perm_hi16u(u0, u1);
}

__device__ __forceinline__ bf16x8 pack8_rhu(const float* x) {
    uintx4 h;
#pragma unroll
    for (int j = 0; j < 4; ++j) h[j] = pack2_rhu(x[2 * j], x[2 * j + 1]);
    return __builtin_bit_cast(bf16x8, h);
}

// hi/lo exact split (proj only): hi = trunc bf16, lo = bf16(x - hi)
__device__ __forceinline__ void pack_split(const float* x, bf16x8& hi, bf16x8& lo) {
    uintx4 h, l;
#pragma unroll
    for (int j = 0; j < 4; ++j) {
        float x0 = x[2 * j], x1 = x[2 * j + 1];
        unsigned u0 = __builtin_bit_cast(unsigned, x0);
        unsigned u1 = __builtin_bit_cast(unsigned, x1);
        h[j] = perm_hi16u(u0, u1);
        float hf0 = __builtin_bit_cast(float, u0 & 0xFFFF0000u);
        float hf1 = __builtin_bit_cast(float, u1 & 0xFFFF0000u);
        l[j] = pack2_rhu(x0 - hf0, x1 - hf1);
    }
    hi = __builtin_bit_cast(bf16x8, h);
    lo = __builtin_bit_cast(bf16x8, l);
}

__device__ __forceinline__ float fast_silu(float x) {
    return x * __builtin_amdgcn_rcpf(1.0f + __expf(-x));
}

// full-rate 16-lane row reduction: v_add_f32 + dpp row_ror 1,2,4,8
__device__ __forceinline__ float rowsum16(float s) {
    int b;
    b = __builtin_bit_cast(int, s);
    b = __builtin_amdgcn_update_dpp(b, b, 0x121, 0xF, 0xF, false);  // ror:1
    s += __builtin_bit_cast(float, b);
    b = __builtin_bit_cast(int, s);
    b = __builtin_amdgcn_update_dpp(b, b, 0x122, 0xF, 0xF, false);  // ror:2
    s += __builtin_bit_cast(float, b);
    b = __builtin_bit_cast(int, s);
    b = __builtin_amdgcn_update_dpp(b, b, 0x124, 0xF, 0xF, false);  // ror:4
    s += __builtin_bit_cast(float, b);
    b = __builtin_bit_cast(int, s);
    b = __builtin_amdgcn_update_dpp(b, b, 0x128, 0xF, 0xF, false);  // ror:8
    s += __builtin_bit_cast(float, b);
    return s;
}

// ---------------------------------------------------------------------------
// Kernel 1: Z[m][n] = X[m] @ W1[n] (+ b1[n] if m is a ligand row)
//   768 blocks = 384 row-tile groups x 2 N-halves; hi/lo split -> Z ~exact.
// ---------------------------------------------------------------------------
__global__ __launch_bounds__(256) void proj_kernel(
    const float* __restrict__ s_lig, const float* __restrict__ s_poc,
    const float* __restrict__ W1,    const float* __restrict__ b1,
    float* __restrict__ Z)
{
    __shared__ unsigned short w1s[64 * W1_LDS_STRIDE];   // 33.8 KB

    const int tid  = threadIdx.x;
    const int tg   = blockIdx.x >> 1;             // row-tile group 0..383
    const int half = blockIdx.x & 1;              // N half

    {
        const f32x4* w4 = (const f32x4*)(W1 + (size_t)half * 64 * SDIM);  // 4096 units
#pragma unroll
        for (int r = 0; r < 2; ++r) {
            f32x4 t[8];
#pragma unroll
            for (int s = 0; s < 8; ++s) t[s] = w4[tid + (r * 8 + s) * 256];
#pragma unroll
            for (int s = 0; s < 8; ++s) {
                const int u = tid + (r * 8 + s) * 256;
                const int n = u >> 6;             // 64 f32x4 per 256-col row
                const int k4 = u & 63;
                ushortx4 us;
#pragma unroll
                for (int j = 0; j < 4; ++j) us[j] = f2bf(t[s][j]);
                *(ushortx4*)(&w1s[n * W1_LDS_STRIDE + k4 * 4]) = us;
            }
        }
    }
    __syncthreads();

    const int lane = tid & 63;
    const int widx = tid >> 6;
    const int c    = lane & 15;
    const int q    = lane >> 4;
    const int tile = tg * 4 + widx;               // 0..1535
    const int row  = tile * 16 + c;

    const float* src = (row < NL_TOT) ? (s_lig + (size_t)row * SDIM)
                                      : (s_poc + (size_t)(row - NL_TOT) * SDIM);

    f32x4 acc[4];
#pragma unroll
    for (int nt = 0; nt < 4; ++nt) acc[nt] = (f32x4){0.f, 0.f, 0.f, 0.f};

#pragma unroll
    for (int ks = 0; ks < 8; ++ks) {              // K = 256 = 8 x 32
        const int k0 = ks * 32 + q * 8;
        f32x4 xa = *reinterpret_cast<const f32x4*>(src + k0);
        f32x4 xb = *reinterpret_cast<const f32x4*>(src + k0 + 4);
        float xv[8] = {xa[0], xa[1], xa[2], xa[3], xb[0], xb[1], xb[2], xb[3]};
        bf16x8 ahi, alo;
        pack_split(xv, ahi, alo);
        bf16x8 bfrag[4];
#pragma unroll
        for (int nt = 0; nt < 4; ++nt)
            bfrag[nt] = *reinterpret_cast<const bf16x8*>(
                &w1s[(nt * 16 + c) * W1_LDS_STRIDE + k0]);
#pragma unroll
        for (int nt = 0; nt < 4; ++nt)            // hi pass (dep distance 4)
            acc[nt] = __builtin_amdgcn_mfma_f32_16x16x32_bf16(ahi, bfrag[nt], acc[nt], 0, 0, 0);
#pragma unroll
        for (int nt = 0; nt < 4; ++nt)            // lo pass
            acc[nt] = __builtin_amdgcn_mfma_f32_16x16x32_bf16(alo, bfrag[nt], acc[nt], 0, 0, 0);
    }

    // C/D layout: col n' = lane&15, row m = q*4 + reg
    const int mb = tile * 16 + q * 4;
#pragma unroll
    for (int nt = 0; nt < 4; ++nt) {
        const int n = half * 64 + nt * 16 + c;
        const float bias = b1[n];
#pragma unroll
        for (int r = 0; r < 4; ++r) {
            const int m = mb + r;
            float v = acc[nt][r];
            if (m < NL_TOT) v += bias;            // fold b1 into ligand rows only
            Z[(size_t)m * H1DIM + n] = v;
        }
    }
}

// ---------------------------------------------------------------------------
// Kernel 2: block = (complex b, 16-pocket chunk jt). 1280 blocks x 4 waves,
//   8 ligand atoms per wave processed as 4 PAIRS: one set of W2-frag/pocket
//   LDS reads per ks feeds two atoms' silu+pack+MFMA.
// ---------------------------------------------------------------------------
__global__ __launch_bounds__(256) void edge_kernel(
    const float* __restrict__ Z,
    const float* __restrict__ W2, const float* __restrict__ b2,
    const float* __restrict__ W3, const float* __restrict__ b3,
    float* __restrict__ out)
{
    __shared__ float zp[JT_CHUNK * ZP_STRIDE];            // 8.4 KB
    __shared__ unsigned short w2s[16 * 64 * 8];           // 16 KB frag-ordered

    const int tid = threadIdx.x;
    const int bid = blockIdx.x;
    const int b   = bid / 10;
    const int jt  = bid - b * 10;

    // stage pocket rows: 16 rows x 128 f32 = 512 f32x4, 2 per thread
    {
        const float* zpg = Z + (size_t)(NL_TOT + b * NPB + jt * JT_CHUNK) * H1DIM;
#pragma unroll
        for (int s = 0; s < 2; ++s) {
            const int u   = tid + s * 256;
            const int row = u >> 5;
            const int c4  = u & 31;
            f32x4 v = *(const f32x4*)(zpg + (size_t)row * H1DIM + c4 * 4);
            *(f32x4*)(&zp[row * ZP_STRIDE + c4 * 4]) = v;
        }
    }

    // stage W2 as bf16 B-fragments, fragment-ordered (see R6):
    //   slot = chunk*64 + lane, chunk = nt*4 + ks;
    //   frag(lane) = W2[n = nt*16 + (lane&15)][ks*32 + (lane>>4)*8 .. +8]
    {
#pragma unroll
        for (int s = 0; s < 4; ++s) {
            const int slot   = tid + s * 256;             // 0..1023
            const int lane_s = slot & 63;
            const int chunk  = slot >> 6;
            const int nt     = chunk >> 2;
            const int ks     = chunk & 3;
            const int n      = nt * 16 + (lane_s & 15);
            const int k0     = ks * 32 + (lane_s >> 4) * 8;
            const float* wsrc = W2 + (size_t)n * H1DIM + k0;
            f32x4 wa = *(const f32x4*)wsrc;
            f32x4 wb = *(const f32x4*)(wsrc + 4);
            float wv[8] = {wa[0], wa[1], wa[2], wa[3], wb[0], wb[1], wb[2], wb[3]};
            ushortx8 us;
#pragma unroll
            for (int j = 0; j < 8; ++j) us[j] = f2bf(wv[j]);   // RNE for weights
            *(ushortx8*)(&w2s[slot * 8]) = us;
        }
    }

    const int lane = tid & 63;
    const int widx = tid >> 6;
    const int c    = lane & 15;
    const int q    = lane >> 4;

    float b2f[4], w3f[4];
#pragma unroll
    for (int nt = 0; nt < 4; ++nt) {
        b2f[nt] = b2[nt * 16 + c];
        w3f[nt] = W3[nt * 16 + c];
    }
    const float b3v = b3[0];

    __syncthreads();

    const float* lgbase = Z + (size_t)(b * NLB) * H1DIM;   // ligand rows of b
    const float* prow   = &zp[c * ZP_STRIDE];
    const unsigned short* wbase = &w2s[lane * 8];          // + chunk*512 ushorts

    // load atoms 0,1 (pair 0)
    f32x4 lgA[4][2], lgB[4][2];
    {
        const float* lr0 = lgbase + (size_t)(widx * 8) * H1DIM;
#pragma unroll
        for (int ks = 0; ks < 4; ++ks) {
            const int k0 = ks * 32 + q * 8;
            lgA[ks][0] = *(const f32x4*)(lr0 + k0);
            lgA[ks][1] = *(const f32x4*)(lr0 + k0 + 4);
            lgB[ks][0] = *(const f32x4*)(lr0 + H1DIM + k0);
            lgB[ks][1] = *(const f32x4*)(lr0 + H1DIM + k0 + 4);
        }
    }

    for (int pair = 0; pair < 4; ++pair) {
        const int i0 = widx * 8 + pair * 2;        // atoms i0, i0+1

        // b2 folded into acc init (saves epilogue adds)
        f32x4 acc0[4], acc1[4];
#pragma unroll
        for (int nt = 0; nt < 4; ++nt) {
            const float bb = b2f[nt];
            acc0[nt] = (f32x4){bb, bb, bb, bb};
            acc1[nt] = (f32x4){bb, bb, bb, bb};
        }

#pragma unroll
        for (int ks = 0; ks < 4; ++ks) {           // K = 128 = 4 x 32
            const int k0 = ks * 32 + q * 8;
            bf16x8 bfr[4];
#pragma unroll
            for (int nt = 0; nt < 4; ++nt)         // conflict-free ds_read_b128
                bfr[nt] = *(const bf16x8*)(wbase + (nt * 4 + ks) * 512);
            f32x4 pa = *(const f32x4*)(prow + k0);
            f32x4 pb = *(const f32x4*)(prow + k0 + 4);
            float hv0[8], hv1[8];
#pragma unroll
            for (int j = 0; j < 4; ++j) {
                hv0[j]     = fast_silu(pa[j] + lgA[ks][0][j]);
                hv0[4 + j] = fast_silu(pb[j] + lgA[ks][1][j]);
                hv1[j]     = fast_silu(pa[j] + lgB[ks][0][j]);
                hv1[4 + j] = fast_silu(pb[j] + lgB[ks][1][j]);
            }
            bf16x8 a0 = pack8_rhu(hv0);
            bf16x8 a1 = pack8_rhu(hv1);
#pragma unroll
            for (int nt = 0; nt < 4; ++nt)         // 8 independent MFMAs
                acc0[nt] = __builtin_amdgcn_mfma_f32_16x16x32_bf16(a0, bfr[nt], acc0[nt], 0, 0, 0);
#pragma unroll
            for (int nt = 0; nt < 4; ++nt)
                acc1[nt] = __builtin_amdgcn_mfma_f32_16x16x32_bf16(a1, bfr[nt], acc1[nt], 0, 0, 0);
        }

        // prefetch next pair (atoms i0+2, i0+3) into the now-dead lg buffers.
        // ABSOLUTE addressing (v10 bug: also bumped lgbase -> skipped rows).
        // Last pair prefetches rows <= b*32+33 <= 4097 < 24576: valid memory,
        // never consumed.
        {
            const float* lrn = lgbase + (size_t)(i0 + 2) * H1DIM;
#pragma unroll
            for (int ks = 0; ks < 4; ++ks) {
                const int k0 = ks * 32 + q * 8;
                lgA[ks][0] = *(const f32x4*)(lrn + k0);
                lgA[ks][1] = *(const f32x4*)(lrn + k0 + 4);
                lgB[ks][0] = *(const f32x4*)(lrn + H1DIM + k0);
                lgB[ks][1] = *(const f32x4*)(lrn + H1DIM + k0 + 4);
            }
        }

        // epilogues (b2 already in acc): lane holds D[m=q*4+r][n=nt*16+c]
#pragma unroll
        for (int at = 0; at < 2; ++at) {
            const f32x4* A = at ? acc1 : acc0;
            float s0 = 0.f, s1 = 0.f, s2 = 0.f, s3 = 0.f;
#pragma unroll
            for (int nt = 0; nt < 4; ++nt) {
                s0 += fast_silu(A[nt][0]) * w3f[nt];
                s1 += fast_silu(A[nt][1]) * w3f[nt];
                s2 += fast_silu(A[nt][2]) * w3f[nt];
                s3 += fast_silu(A[nt][3]) * w3f[nt];
            }
            s0 = rowsum16(s0);
            s1 = rowsum16(s1);
            s2 = rowsum16(s2);
            s3 = rowsum16(s3);
            if (c < 4) {
                float v = (c == 0) ? s0 : (c == 1) ? s1 : (c == 2) ? s2 : s3;
                const int e0 = (b * NLB + i0 + at) * NPB + jt * JT_CHUNK;
                out[e0 + q * 4 + c] = fmaxf(v + b3v, 0.0f);
            }
        }
    }
}

// ---------------------------------------------------------------------------
extern "C" void kernel_launch(void* const* d_in, const int* in_sizes, int n_in,
                              void* d_out, int out_size, void* d_ws, size_t ws_size,
                              hipStream_t stream)
{
    const float* s_lig = (const float*)d_in[0];
    const float* s_poc = (const float*)d_in[1];
    const float* W1    = (const float*)d_in[4];
    const float* b1    = (const float*)d_in[5];
    const float* W2    = (const float*)d_in[6];
    const float* b2    = (const float*)d_in[7];
    const float* W3    = (const float*)d_in[8];
    const float* b3    = (const float*)d_in[9];

    float* Z = (float*)d_ws;   // NROWS*H1DIM*4 = 12.58 MB workspace

    hipLaunchKernelGGL(proj_kernel, dim3(NROWS / 16 / 4 * 2), dim3(256), 0, stream,
                       s_lig, s_poc, W1, b1, Z);
    hipLaunchKernelGGL(edge_kernel, dim3(B_CPLX * 10), dim3(256), 0, stream,
                       Z, W2, b2, W3, b3, (float*)d_out);
}

// Round 12
// 138.227 us; speedup vs baseline: 1.0149x; 1.0149x over previous
//
#include <hip/hip_runtime.h>
#include <hip/hip_bf16.h>

// ---------------------------------------------------------------------------
// HiddenEdgeDistanceMLP on MI355X (gfx950)
//
// reference:  s = s_lig[l] + s_poc[p]          [E,256]
//             h1 = silu(s @ W1.T + b1)         [E,128]
//             h2 = silu(h1 @ W2.T + b2)        [E,64]
//             out = relu(h2 @ W3.T + b3)       [E]
//
// Factorization: Z = concat(s_lig, s_poc) @ W1.T precomputed once (proj, fp32,
// hi/lo-split MFMA so Z is near-exact); b1 folded into ligand rows. Edge
// structure is block-diagonal and regular:
//   e = (b*32 + i)*160 + j,  l[e] = b*32+i,  p[e] = b*160+j
//
// edge v12 (R11 post-mortem: VALUBusy pinned ~67% == 5-blocks-on-4-slots
// packing limit; per-wave work inventory matches busy time):
//  * block = (b, jt, atom-half) -> 2560 blocks, 4 waves x 4 atoms (2 pairs).
//    B=10 blocks/CU on R=4 co-resident -> ceil(10/4)=3 batches = 83% packing
//    (was 5 on 4 -> 62.5%). Staging duplicates (+~1.5us, FETCH ~20MB) —
//    cheap vs the packing win. Unlike R5's failed split, the kernel is now
//    work-bound and W2 staging is LDS-shared, not per-wave register work.
// v11 mechanisms kept: 2-atoms-per-K-pass (shared W2-frag + pocket reads),
// absolute-addressed prefetch into dead lg buffers under the epilogue,
// b2 folded into acc init, single rhu-bf16 h1 + 1 MFMA/nt (absmax 1.95e-3),
// pocket rows + W2 B-frags in LDS, DPP rowsum, perm packing, no min-waves
// bound (R3: VGPR cliff -> spills).
// ---------------------------------------------------------------------------

#define B_CPLX   128
#define NLB      32
#define NPB      160
#define SDIM     256
#define H1DIM    128
#define NL_TOT   (B_CPLX * NLB)         // 4096
#define NP_TOT   (B_CPLX * NPB)         // 20480
#define NROWS    (NL_TOT + NP_TOT)      // 24576
#define E_TOT    (B_CPLX * NLB * NPB)   // 655360

#define W1_LDS_STRIDE 264               // 256 + 8 bf16 pad
#define JT_CHUNK 16                     // pocket rows per block
#define ZP_STRIDE 132                   // 128 + 4 f32 pad

typedef __bf16 bf16x8 __attribute__((ext_vector_type(8)));
typedef unsigned short ushortx8 __attribute__((ext_vector_type(8)));
typedef unsigned short ushortx4 __attribute__((ext_vector_type(4)));
typedef unsigned uintx4 __attribute__((ext_vector_type(4)));
typedef float f32x4 __attribute__((ext_vector_type(4)));

__device__ __forceinline__ unsigned short f2bf(float f) {
    unsigned u = __builtin_bit_cast(unsigned, f);
    u += 0x7FFFu + ((u >> 16) & 1u);          // round-to-nearest-even
    return (unsigned short)(u >> 16);
}

// v_perm_b32: pack hi16(x0) low, hi16(x1) high (1 op)
__device__ __forceinline__ unsigned perm_hi16u(unsigned u0, unsigned u1) {
    return __builtin_amdgcn_perm(u1, u0, 0x07060302u);
}

// round-half-up bf16 pair pack: bitpattern + 0x8000 then take hi16.
__device__ __forceinline__ unsigned pack2_rhu(float x0, float x1) {
    unsigned u0 = __builtin_bit_cast(unsigned, x0) + 0x8000u;
    unsigned u1 = __builtin_bit_cast(unsigned, x1) + 0x8000u;
    return perm_hi16u(u0, u1);
}

__device__ __forceinline__ bf16x8 pack8_rhu(const float* x) {
    uintx4 h;
#pragma unroll
    for (int j = 0; j < 4; ++j) h[j] = pack2_rhu(x[2 * j], x[2 * j + 1]);
    return __builtin_bit_cast(bf16x8, h);
}

// hi/lo exact split (proj only): hi = trunc bf16, lo = bf16(x - hi)
__device__ __forceinline__ void pack_split(const float* x, bf16x8& hi, bf16x8& lo) {
    uintx4 h, l;
#pragma unroll
    for (int j = 0; j < 4; ++j) {
        float x0 = x[2 * j], x1 = x[2 * j + 1];
        unsigned u0 = __builtin_bit_cast(unsigned, x0);
        unsigned u1 = __builtin_bit_cast(unsigned, x1);
        h[j] = perm_hi16u(u0, u1);
        float hf0 = __builtin_bit_cast(float, u0 & 0xFFFF0000u);
        float hf1 = __builtin_bit_cast(float, u1 & 0xFFFF0000u);
        l[j] = pack2_rhu(x0 - hf0, x1 - hf1);
    }
    hi = __builtin_bit_cast(bf16x8, h);
    lo = __builtin_bit_cast(bf16x8, l);
}

__device__ __forceinline__ float fast_silu(float x) {
    return x * __builtin_amdgcn_rcpf(1.0f + __expf(-x));
}

// full-rate 16-lane row reduction: v_add_f32 + dpp row_ror 1,2,4,8
__device__ __forceinline__ float rowsum16(float s) {
    int b;
    b = __builtin_bit_cast(int, s);
    b = __builtin_amdgcn_update_dpp(b, b, 0x121, 0xF, 0xF, false);  // ror:1
    s += __builtin_bit_cast(float, b);
    b = __builtin_bit_cast(int, s);
    b = __builtin_amdgcn_update_dpp(b, b, 0x122, 0xF, 0xF, false);  // ror:2
    s += __builtin_bit_cast(float, b);
    b = __builtin_bit_cast(int, s);
    b = __builtin_amdgcn_update_dpp(b, b, 0x124, 0xF, 0xF, false);  // ror:4
    s += __builtin_bit_cast(float, b);
    b = __builtin_bit_cast(int, s);
    b = __builtin_amdgcn_update_dpp(b, b, 0x128, 0xF, 0xF, false);  // ror:8
    s += __builtin_bit_cast(float, b);
    return s;
}

// ---------------------------------------------------------------------------
// Kernel 1: Z[m][n] = X[m] @ W1[n] (+ b1[n] if m is a ligand row)
//   768 blocks = 384 row-tile groups x 2 N-halves; hi/lo split -> Z ~exact.
// ---------------------------------------------------------------------------
__global__ __launch_bounds__(256) void proj_kernel(
    const float* __restrict__ s_lig, const float* __restrict__ s_poc,
    const float* __restrict__ W1,    const float* __restrict__ b1,
    float* __restrict__ Z)
{
    __shared__ unsigned short w1s[64 * W1_LDS_STRIDE];   // 33.8 KB

    const int tid  = threadIdx.x;
    const int tg   = blockIdx.x >> 1;             // row-tile group 0..383
    const int half = blockIdx.x & 1;              // N half

    {
        const f32x4* w4 = (const f32x4*)(W1 + (size_t)half * 64 * SDIM);  // 4096 units
#pragma unroll
        for (int r = 0; r < 2; ++r) {
            f32x4 t[8];
#pragma unroll
            for (int s = 0; s < 8; ++s) t[s] = w4[tid + (r * 8 + s) * 256];
#pragma unroll
            for (int s = 0; s < 8; ++s) {
                const int u = tid + (r * 8 + s) * 256;
                const int n = u >> 6;             // 64 f32x4 per 256-col row
                const int k4 = u & 63;
                ushortx4 us;
#pragma unroll
                for (int j = 0; j < 4; ++j) us[j] = f2bf(t[s][j]);
                *(ushortx4*)(&w1s[n * W1_LDS_STRIDE + k4 * 4]) = us;
            }
        }
    }
    __syncthreads();

    const int lane = tid & 63;
    const int widx = tid >> 6;
    const int c    = lane & 15;
    const int q    = lane >> 4;
    const int tile = tg * 4 + widx;               // 0..1535
    const int row  = tile * 16 + c;

    const float* src = (row < NL_TOT) ? (s_lig + (size_t)row * SDIM)
                                      : (s_poc + (size_t)(row - NL_TOT) * SDIM);

    f32x4 acc[4];
#pragma unroll
    for (int nt = 0; nt < 4; ++nt) acc[nt] = (f32x4){0.f, 0.f, 0.f, 0.f};

#pragma unroll
    for (int ks = 0; ks < 8; ++ks) {              // K = 256 = 8 x 32
        const int k0 = ks * 32 + q * 8;
        f32x4 xa = *reinterpret_cast<const f32x4*>(src + k0);
        f32x4 xb = *reinterpret_cast<const f32x4*>(src + k0 + 4);
        float xv[8] = {xa[0], xa[1], xa[2], xa[3], xb[0], xb[1], xb[2], xb[3]};
        bf16x8 ahi, alo;
        pack_split(xv, ahi, alo);
        bf16x8 bfrag[4];
#pragma unroll
        for (int nt = 0; nt < 4; ++nt)
            bfrag[nt] = *reinterpret_cast<const bf16x8*>(
                &w1s[(nt * 16 + c) * W1_LDS_STRIDE + k0]);
#pragma unroll
        for (int nt = 0; nt < 4; ++nt)            // hi pass (dep distance 4)
            acc[nt] = __builtin_amdgcn_mfma_f32_16x16x32_bf16(ahi, bfrag[nt], acc[nt], 0, 0, 0);
#pragma unroll
        for (int nt = 0; nt < 4; ++nt)            // lo pass
            acc[nt] = __builtin_amdgcn_mfma_f32_16x16x32_bf16(alo, bfrag[nt], acc[nt], 0, 0, 0);
    }

    // C/D layout: col n' = lane&15, row m = q*4 + reg
    const int mb = tile * 16 + q * 4;
#pragma unroll
    for (int nt = 0; nt < 4; ++nt) {
        const int n = half * 64 + nt * 16 + c;
        const float bias = b1[n];
#pragma unroll
        for (int r = 0; r < 4; ++r) {
            const int m = mb + r;
            float v = acc[nt][r];
            if (m < NL_TOT) v += bias;            // fold b1 into ligand rows only
            Z[(size_t)m * H1DIM + n] = v;
        }
    }
}

// ---------------------------------------------------------------------------
// Kernel 2: block = (complex b, 16-pocket chunk jt, atom-half ih).
//   2560 blocks x 4 waves; each wave: 4 atoms = 2 pairs. One set of
//   W2-frag/pocket LDS reads per ks feeds both atoms of a pair.
// ---------------------------------------------------------------------------
__global__ __launch_bounds__(256) void edge_kernel(
    const float* __restrict__ Z,
    const float* __restrict__ W2, const float* __restrict__ b2,
    const float* __restrict__ W3, const float* __restrict__ b3,
    float* __restrict__ out)
{
    __shared__ float zp[JT_CHUNK * ZP_STRIDE];            // 8.4 KB
    __shared__ unsigned short w2s[16 * 64 * 8];           // 16 KB frag-ordered

    const int tid = threadIdx.x;
    const int bid = blockIdx.x;
    const int b   = bid / 20;
    const int rem = bid - b * 20;
    const int jt  = rem >> 1;                     // 0..9
    const int ih  = rem & 1;                      // atom half: atoms [ih*16, ih*16+16)

    // stage pocket rows: 16 rows x 128 f32 = 512 f32x4, 2 per thread
    {
        const float* zpg = Z + (size_t)(NL_TOT + b * NPB + jt * JT_CHUNK) * H1DIM;
#pragma unroll
        for (int s = 0; s < 2; ++s) {
            const int u   = tid + s * 256;
            const int row = u >> 5;
            const int c4  = u & 31;
            f32x4 v = *(const f32x4*)(zpg + (size_t)row * H1DIM + c4 * 4);
            *(f32x4*)(&zp[row * ZP_STRIDE + c4 * 4]) = v;
        }
    }

    // stage W2 as bf16 B-fragments, fragment-ordered (see R6):
    //   slot = chunk*64 + lane, chunk = nt*4 + ks;
    //   frag(lane) = W2[n = nt*16 + (lane&15)][ks*32 + (lane>>4)*8 .. +8]
    {
#pragma unroll
        for (int s = 0; s < 4; ++s) {
            const int slot   = tid + s * 256;             // 0..1023
            const int lane_s = slot & 63;
            const int chunk  = slot >> 6;
            const int nt     = chunk >> 2;
            const int ks     = chunk & 3;
            const int n      = nt * 16 + (lane_s & 15);
            const int k0     = ks * 32 + (lane_s >> 4) * 8;
            const float* wsrc = W2 + (size_t)n * H1DIM + k0;
            f32x4 wa = *(const f32x4*)wsrc;
            f32x4 wb = *(const f32x4*)(wsrc + 4);
            float wv[8] = {wa[0], wa[1], wa[2], wa[3], wb[0], wb[1], wb[2], wb[3]};
            ushortx8 us;
#pragma unroll
            for (int j = 0; j < 8; ++j) us[j] = f2bf(wv[j]);   // RNE for weights
            *(ushortx8*)(&w2s[slot * 8]) = us;
        }
    }

    const int lane = tid & 63;
    const int widx = tid >> 6;
    const int c    = lane & 15;
    const int q    = lane >> 4;

    float b2f[4], w3f[4];
#pragma unroll
    for (int nt = 0; nt < 4; ++nt) {
        b2f[nt] = b2[nt * 16 + c];
        w3f[nt] = W3[nt * 16 + c];
    }
    const float b3v = b3[0];

    __syncthreads();

    const float* lgbase = Z + (size_t)(b * NLB) * H1DIM;   // ligand rows of b
    const float* prow   = &zp[c * ZP_STRIDE];
    const unsigned short* wbase = &w2s[lane * 8];          // + chunk*512 ushorts

    const int a0 = ih * 16 + widx * 4;             // wave's first atom (0..28)

    // load atoms a0, a0+1 (pair 0)
    f32x4 lgA[4][2], lgB[4][2];
    {
        const float* lr0 = lgbase + (size_t)a0 * H1DIM;
#pragma unroll
        for (int ks = 0; ks < 4; ++ks) {
            const int k0 = ks * 32 + q * 8;
            lgA[ks][0] = *(const f32x4*)(lr0 + k0);
            lgA[ks][1] = *(const f32x4*)(lr0 + k0 + 4);
            lgB[ks][0] = *(const f32x4*)(lr0 + H1DIM + k0);
            lgB[ks][1] = *(const f32x4*)(lr0 + H1DIM + k0 + 4);
        }
    }

#pragma unroll
    for (int pair = 0; pair < 2; ++pair) {
        const int i0 = a0 + pair * 2;              // atoms i0, i0+1

        // b2 folded into acc init (saves epilogue adds)
        f32x4 acc0[4], acc1[4];
#pragma unroll
        for (int nt = 0; nt < 4; ++nt) {
            const float bb = b2f[nt];
            acc0[nt] = (f32x4){bb, bb, bb, bb};
            acc1[nt] = (f32x4){bb, bb, bb, bb};
        }

#pragma unroll
        for (int ks = 0; ks < 4; ++ks) {           // K = 128 = 4 x 32
            const int k0 = ks * 32 + q * 8;
            bf16x8 bfr[4];
#pragma unroll
            for (int nt = 0; nt < 4; ++nt)         // conflict-free ds_read_b128
                bfr[nt] = *(const bf16x8*)(wbase + (nt * 4 + ks) * 512);
            f32x4 pa = *(const f32x4*)(prow + k0);
            f32x4 pb = *(const f32x4*)(prow + k0 + 4);
            float hv0[8], hv1[8];
#pragma unroll
            for (int j = 0; j < 4; ++j) {
                hv0[j]     = fast_silu(pa[j] + lgA[ks][0][j]);
                hv0[4 + j] = fast_silu(pb[j] + lgA[ks][1][j]);
                hv1[j]     = fast_silu(pa[j] + lgB[ks][0][j]);
                hv1[4 + j] = fast_silu(pb[j] + lgB[ks][1][j]);
            }
            bf16x8 a0f = pack8_rhu(hv0);
            bf16x8 a1f = pack8_rhu(hv1);
#pragma unroll
            for (int nt = 0; nt < 4; ++nt)         // 8 independent MFMAs
                acc0[nt] = __builtin_amdgcn_mfma_f32_16x16x32_bf16(a0f, bfr[nt], acc0[nt], 0, 0, 0);
#pragma unroll
            for (int nt = 0; nt < 4; ++nt)
                acc1[nt] = __builtin_amdgcn_mfma_f32_16x16x32_bf16(a1f, bfr[nt], acc1[nt], 0, 0, 0);
        }

        // prefetch next pair (atoms i0+2, i0+3) into the now-dead lg buffers.
        // ABSOLUTE addressing (v10 bug: also bumped base -> skipped rows).
        // Last prefetch touches rows <= b*32+33 <= 4097 < 24576: valid
        // memory, never consumed.
        {
            const float* lrn = lgbase + (size_t)(i0 + 2) * H1DIM;
#pragma unroll
            for (int ks = 0; ks < 4; ++ks) {
                const int k0 = ks * 32 + q * 8;
                lgA[ks][0] = *(const f32x4*)(lrn + k0);
                lgA[ks][1] = *(const f32x4*)(lrn + k0 + 4);
                lgB[ks][0] = *(const f32x4*)(lrn + H1DIM + k0);
                lgB[ks][1] = *(const f32x4*)(lrn + H1DIM + k0 + 4);
            }
        }

        // epilogues (b2 already in acc): lane holds D[m=q*4+r][n=nt*16+c]
#pragma unroll
        for (int at = 0; at < 2; ++at) {
            const f32x4* A = at ? acc1 : acc0;
            float s0 = 0.f, s1 = 0.f, s2 = 0.f, s3 = 0.f;
#pragma unroll
            for (int nt = 0; nt < 4; ++nt) {
                s0 += fast_silu(A[nt][0]) * w3f[nt];
                s1 += fast_silu(A[nt][1]) * w3f[nt];
                s2 += fast_silu(A[nt][2]) * w3f[nt];
                s3 += fast_silu(A[nt][3]) * w3f[nt];
            }
            s0 = rowsum16(s0);
            s1 = rowsum16(s1);
            s2 = rowsum16(s2);
            s3 = rowsum16(s3);
            if (c < 4) {
                float v = (c == 0) ? s0 : (c == 1) ? s1 : (c == 2) ? s2 : s3;
                const int e0 = (b * NLB + i0 + at) * NPB + jt * JT_CHUNK;
                out[e0 + q * 4 + c] = fmaxf(v + b3v, 0.0f);
            }
        }
    }
}

// ---------------------------------------------------------------------------
extern "C" void kernel_launch(void* const* d_in, const int* in_sizes, int n_in,
                              void* d_out, int out_size, void* d_ws, size_t ws_size,
                              hipStream_t stream)
{
    const float* s_lig = (const float*)d_in[0];
    const float* s_poc = (const float*)d_in[1];
    const float* W1    = (const float*)d_in[4];
    const float* b1    = (const float*)d_in[5];
    const float* W2    = (const float*)d_in[6];
    const float* b2    = (const float*)d_in[7];
    const float* W3    = (const float*)d_in[8];
    const float* b3    = (const float*)d_in[9];

    float* Z = (float*)d_ws;   // NROWS*H1DIM*4 = 12.58 MB workspace

    hipLaunchKernelGGL(proj_kernel, dim3(NROWS / 16 / 4 * 2), dim3(256), 0, stream,
                       s_lig, s_poc, W1, b1, Z);
    hipLaunchKernelGGL(edge_kernel, dim3(B_CPLX * 20), dim3(256), 0, stream,
                       Z, W2, b2, W3, b3, (float*)d_out);
}